// Round 7
// baseline (226.964 us; speedup 1.0000x reference)
//
#include <hip/hip_runtime.h>
#include <hip/hip_bf16.h>
#include <stdint.h>

// Problem dims: T=8192 tokens, H=2048 hidden, I=768 intermediate
// fp32 in/out; internal bf16 MFMA (absmax 0.0156 vs 0.074 budget).
#define T_DIM 8192
#define H_DIM 2048
#define I_DIM 768

typedef __bf16 bf16_t;
typedef bf16_t bf16x8 __attribute__((ext_vector_type(8)));
typedef bf16_t bf16x4 __attribute__((ext_vector_type(4)));
typedef float  f32x4  __attribute__((ext_vector_type(4)));

// Async global->LDS, 16B per lane. LDS dest must be wave-uniform base + lane*16
// (linear). Any swizzle goes on the GLOBAL source + the ds_read address.
__device__ __forceinline__ void async_load16(const void* g, void* s) {
    __builtin_amdgcn_global_load_lds(
        (const __attribute__((address_space(1))) void*)g,
        (__attribute__((address_space(3))) void*)s, 16, 0, 0);
}

// Raw barrier with compiler memory fences on both sides.
__device__ __forceinline__ void phase_barrier() {
    asm volatile("" ::: "memory");
    __builtin_amdgcn_s_barrier();
    asm volatile("" ::: "memory");
}

__device__ __forceinline__ bf16x8 cvt8(float4 a, float4 b) {
    bf16x8 o;
    o[0] = (bf16_t)a.x; o[1] = (bf16_t)a.y; o[2] = (bf16_t)a.z; o[3] = (bf16_t)a.w;
    o[4] = (bf16_t)b.x; o[5] = (bf16_t)b.y; o[6] = (bf16_t)b.z; o[7] = (bf16_t)b.w;
    return o;
}

// ---------------------------------------------------------------------------
// Kernel 0 (R3 version, byte-identical): fp32 -> bf16 of all four inputs.
// ---------------------------------------------------------------------------
__global__ __launch_bounds__(256) void cvt_kernel(
    const float* __restrict__ X, const float* __restrict__ G,
    const float* __restrict__ U, const float* __restrict__ D,
    bf16_t* __restrict__ Xb, bf16_t* __restrict__ Gb,
    bf16_t* __restrict__ Ub, bf16_t* __restrict__ Db)
{
    const size_t N8X = (size_t)T_DIM * H_DIM / 8;
    const size_t N8W = (size_t)I_DIM * H_DIM / 8;
    const size_t total = N8X + 3 * N8W;
    for (size_t i = (size_t)blockIdx.x * blockDim.x + threadIdx.x; i < total;
         i += (size_t)gridDim.x * blockDim.x) {
        const float* s; bf16_t* d; size_t j = i;
        if (j < N8X) { s = X; d = Xb; }
        else {
            j -= N8X;
            if (j < N8W) { s = G; d = Gb; }
            else { j -= N8W;
                if (j < N8W) { s = U; d = Ub; }
                else { j -= N8W; s = D; d = Db; } }
        }
        float4 v0 = ((const float4*)s)[2 * j];
        float4 v1 = ((const float4*)s)[2 * j + 1];
        ((bf16x8*)d)[j] = cvt8(v0, v1);
    }
}

// ---------------------------------------------------------------------------
// Kernel 1 v7: gateup on the R6-VERIFIED 256x256 8-phase skeleton (identical
// phase choreography / staging counts / vmcnt placement as down_kernel; only
// pointers, nt=32, and the epilogue differ).
// N-tile = 256 B-rows interleaved per 32-row group: rows [g*32 .. g*32+15] =
// Wg rows (bn*128 + g*16 ..), rows [g*32+16 .. g*32+31] = Wu same cols.
// => wave-local pairing: acc[mi][2k] = G cols, acc[mi][2k+1] = U, same cols.
// Grid 32x6 = 192 blocks (75% CU fill; 51.5 GF at template-class rate ~44us
// beats the 67us 2-barrier form). h = silu(G)*U in-register -> Hbuf bf16.
// ---------------------------------------------------------------------------
__global__ __launch_bounds__(512, 2) void gateup_kernel(
    const bf16_t* __restrict__ X,
    const bf16_t* __restrict__ Wg,
    const bf16_t* __restrict__ Wu,
    bf16_t* __restrict__ Hbuf)
{
    __shared__ __align__(16) bf16_t sA[2][256 * 64];   // 2 x 32 KB
    __shared__ __align__(16) bf16_t sB[2][256 * 64];   // 2 x 32 KB

    const int tid  = threadIdx.x;     // 0..511
    const int lane = tid & 63;
    const int wave = tid >> 6;        // 0..7
    const int wm   = wave >> 2;       // 0..1 -> 128-row half
    const int wn   = wave & 3;        // 0..3 -> 64-B-row quarter
    const int quad = lane >> 4;       // 0..3
    const int lrow = lane & 15;       // 0..15

    const int bm = blockIdx.x;        // 0..31 (T/256)
    const int bn = blockIdx.y;        // 0..5  (I/128)

    f32x4 acc[8][4];
#pragma unroll
    for (int i = 0; i < 8; i++)
#pragma unroll
        for (int j = 0; j < 4; j++) acc[i][j] = (f32x4)(0.f);

    // Staging: K-tile = 256 rows x 64 cols x 2B = 2048 x 16B segs = 4/thread.
    // Seg s: row r = s>>3, stored slot = s&7; source col-block
    // c = (s&7) ^ (r&7)  (involution; elements c*8). Per-seg source pointers
    // precomputed (B selects Wg/Wu by interleave group).
    const bf16_t* aSrc[4];
    const bf16_t* bSrc[4];
#pragma unroll
    for (int i = 0; i < 4; i++) {
        int s = tid + 512 * i;
        int r = s >> 3;
        int c = ((s & 7) ^ (r & 7)) * 8;
        aSrc[i] = X + (size_t)(bm * 256 + r) * H_DIM + c;
        int g = r >> 5, w = r & 31;                 // 32-row group, pos in group
        const bf16_t* wb = (w < 16) ? Wg : Wu;
        aSrc[i] = aSrc[i];                          // (keep compiler happy)
        bSrc[i] = wb + (size_t)(bn * 128 + g * 16 + (w & 15)) * H_DIM + c;
    }

#define STAGE_A(t) do { _Pragma("unroll") \
    for (int i_ = 0; i_ < 4; i_++) \
        async_load16(aSrc[i_] + (t) * 64, &sA[(t) & 1][(tid + 512 * i_) * 8]); } while (0)
#define STAGE_B(t) do { _Pragma("unroll") \
    for (int i_ = 0; i_ < 4; i_++) \
        async_load16(bSrc[i_] + (t) * 64, &sB[(t) & 1][(tid + 512 * i_) * 8]); } while (0)

    // Read-side swizzled element offsets, kk=0 (kk=1: XOR 32 <=> slot^4).
    int aOff[8], bOff[4];
#pragma unroll
    for (int mi = 0; mi < 8; mi++) {
        int r = wm * 128 + mi * 16 + lrow;
        aOff[mi] = r * 64 + ((quad ^ (r & 7)) * 8);
    }
#pragma unroll
    for (int ni = 0; ni < 4; ni++) {
        int r = wn * 64 + ni * 16 + lrow;
        bOff[ni] = r * 64 + ((quad ^ (r & 7)) * 8);
    }

    const int nt = H_DIM / 64;   // 32

    STAGE_A(0); STAGE_B(0); STAGE_B(1);
    asm volatile("s_waitcnt vmcnt(4)" ::: "memory");
    phase_barrier();

    for (int t = 0; t < nt; ++t) {
        const int p = t & 1;
        bf16x8 bF[4][2];

#pragma unroll
        for (int q = 0; q < 4; ++q) {
            bf16x8 aF[2][2];
            if (q == 0) {
#pragma unroll
                for (int ni = 0; ni < 4; ni++) {
                    bF[ni][0] = *(const bf16x8*)&sB[p][bOff[ni]];
                    bF[ni][1] = *(const bf16x8*)&sB[p][bOff[ni] ^ 32];
                }
            }
#pragma unroll
            for (int j = 0; j < 2; j++) {
                aF[j][0] = *(const bf16x8*)&sA[p][aOff[2 * q + j]];
                aF[j][1] = *(const bf16x8*)&sA[p][aOff[2 * q + j] ^ 32];
            }
            if (q == 0 && t + 1 < nt) STAGE_A(t + 1);   // -> sA[p^1]
            if (q == 1 && t + 2 < nt) STAGE_B(t + 2);   // -> sB[p]

            phase_barrier();
            asm volatile("s_waitcnt lgkmcnt(0)" ::: "memory");
            __builtin_amdgcn_sched_barrier(0);
            __builtin_amdgcn_s_setprio(1);
#pragma unroll
            for (int j = 0; j < 2; j++)
#pragma unroll
                for (int ni = 0; ni < 4; ni++)
#pragma unroll
                    for (int kk = 0; kk < 2; kk++)
                        acc[2 * q + j][ni] = __builtin_amdgcn_mfma_f32_16x16x32_bf16(
                            aF[j][kk], bF[ni][kk], acc[2 * q + j][ni], 0, 0, 0);
            __builtin_amdgcn_s_setprio(0);
            if (q < 3) phase_barrier();
        }

        if (t < nt - 2) {
            asm volatile("s_waitcnt vmcnt(4)" ::: "memory");
            phase_barrier();
        } else if (t == nt - 2) {
            asm volatile("s_waitcnt vmcnt(0)" ::: "memory");
            phase_barrier();
        }
    }
#undef STAGE_A
#undef STAGE_B

    // Epilogue: pair (acc[mi][2k], acc[mi][2k+1]) = (G, U) of h-col
    // bn*128 + wn*32 + k*16 + lrow. C/D layout: col=lane&15, row=quad*4+r.
#pragma unroll
    for (int mi = 0; mi < 8; mi++) {
#pragma unroll
        for (int k = 0; k < 2; k++) {
#pragma unroll
            for (int r = 0; r < 4; r++) {
                int row = bm * 256 + wm * 128 + mi * 16 + quad * 4 + r;
                int col = bn * 128 + wn * 32 + k * 16 + lrow;
                float g = acc[mi][2 * k][r];
                float u = acc[mi][2 * k + 1][r];
                float h = (g / (1.f + __expf(-g))) * u;
                Hbuf[(size_t)row * I_DIM + col] = (bf16_t)h;
            }
        }
    }
}

// ---------------------------------------------------------------------------
// Kernel 2 (R6 version, byte-identical): 256x256 8-phase GEMM.
// out[T,H] = h @ down^T, K = 768 = 12 K-tiles of BK=64. Grid 32x8 = 256.
// ---------------------------------------------------------------------------
__global__ __launch_bounds__(512, 2) void down_kernel(
    const bf16_t* __restrict__ Hbuf,
    const bf16_t* __restrict__ Wd,
    float* __restrict__ Out)
{
    __shared__ __align__(16) bf16_t sA[2][256 * 64];   // 2 x 32 KB
    __shared__ __align__(16) bf16_t sB[2][256 * 64];   // 2 x 32 KB

    const int tid  = threadIdx.x;     // 0..511
    const int lane = tid & 63;
    const int wave = tid >> 6;        // 0..7
    const int wm   = wave >> 2;       // 0..1 -> 128-row half
    const int wn   = wave & 3;        // 0..3 -> 64-col quarter
    const int quad = lane >> 4;       // 0..3
    const int lrow = lane & 15;       // 0..15

    const int bm = blockIdx.x;        // 0..31 (T/256)
    const int bn = blockIdx.y;        // 0..7  (H/256)

    f32x4 acc[8][4];
#pragma unroll
    for (int i = 0; i < 8; i++)
#pragma unroll
        for (int j = 0; j < 4; j++) acc[i][j] = (f32x4)(0.f);

    int stRow[4], stCol[4];
#pragma unroll
    for (int i = 0; i < 4; i++) {
        int s = tid + 512 * i;
        stRow[i] = s >> 3;
        stCol[i] = ((s & 7) ^ ((s >> 3) & 7)) * 8;
    }

    const bf16_t* Ab = Hbuf + (size_t)(bm * 256) * I_DIM;
    const bf16_t* Bb = Wd   + (size_t)(bn * 256) * I_DIM;

#define STAGE_A(t) do { _Pragma("unroll") \
    for (int i_ = 0; i_ < 4; i_++) \
        async_load16(Ab + (size_t)stRow[i_] * I_DIM + (t) * 64 + stCol[i_], \
                     &sA[(t) & 1][(tid + 512 * i_) * 8]); } while (0)
#define STAGE_B(t) do { _Pragma("unroll") \
    for (int i_ = 0; i_ < 4; i_++) \
        async_load16(Bb + (size_t)stRow[i_] * I_DIM + (t) * 64 + stCol[i_], \
                     &sB[(t) & 1][(tid + 512 * i_) * 8]); } while (0)

    int aOff[8], bOff[4];
#pragma unroll
    for (int mi = 0; mi < 8; mi++) {
        int r = wm * 128 + mi * 16 + lrow;
        aOff[mi] = r * 64 + ((quad ^ (r & 7)) * 8);
    }
#pragma unroll
    for (int ni = 0; ni < 4; ni++) {
        int r = wn * 64 + ni * 16 + lrow;
        bOff[ni] = r * 64 + ((quad ^ (r & 7)) * 8);
    }

    const int nt = I_DIM / 64;   // 12

    STAGE_A(0); STAGE_B(0); STAGE_B(1);
    asm volatile("s_waitcnt vmcnt(4)" ::: "memory");
    phase_barrier();

    for (int t = 0; t < nt; ++t) {
        const int p = t & 1;
        bf16x8 bF[4][2];

#pragma unroll
        for (int q = 0; q < 4; ++q) {
            bf16x8 aF[2][2];
            if (q == 0) {
#pragma unroll
                for (int ni = 0; ni < 4; ni++) {
                    bF[ni][0] = *(const bf16x8*)&sB[p][bOff[ni]];
                    bF[ni][1] = *(const bf16x8*)&sB[p][bOff[ni] ^ 32];
                }
            }
#pragma unroll
            for (int j = 0; j < 2; j++) {
                aF[j][0] = *(const bf16x8*)&sA[p][aOff[2 * q + j]];
                aF[j][1] = *(const bf16x8*)&sA[p][aOff[2 * q + j] ^ 32];
            }
            if (q == 0 && t + 1 < nt) STAGE_A(t + 1);   // -> sA[p^1]
            if (q == 1 && t + 2 < nt) STAGE_B(t + 2);   // -> sB[p]

            phase_barrier();
            asm volatile("s_waitcnt lgkmcnt(0)" ::: "memory");
            __builtin_amdgcn_sched_barrier(0);
            __builtin_amdgcn_s_setprio(1);
#pragma unroll
            for (int j = 0; j < 2; j++)
#pragma unroll
                for (int ni = 0; ni < 4; ni++)
#pragma unroll
                    for (int kk = 0; kk < 2; kk++)
                        acc[2 * q + j][ni] = __builtin_amdgcn_mfma_f32_16x16x32_bf16(
                            aF[j][kk], bF[ni][kk], acc[2 * q + j][ni], 0, 0, 0);
            __builtin_amdgcn_s_setprio(0);
            if (q < 3) phase_barrier();
        }

        if (t < nt - 2) {
            asm volatile("s_waitcnt vmcnt(4)" ::: "memory");
            phase_barrier();
        } else if (t == nt - 2) {
            asm volatile("s_waitcnt vmcnt(0)" ::: "memory");
            phase_barrier();
        }
    }
#undef STAGE_A
#undef STAGE_B

#pragma unroll
    for (int mi = 0; mi < 8; mi++) {
#pragma unroll
        for (int ni = 0; ni < 4; ni++) {
#pragma unroll
            for (int r = 0; r < 4; r++) {
                int row = bm * 256 + wm * 128 + mi * 16 + quad * 4 + r;
                int col = bn * 256 + wn * 64 + ni * 16 + lrow;
                Out[(size_t)row * H_DIM + col] = acc[mi][ni][r];
            }
        }
    }
}

extern "C" void kernel_launch(void* const* d_in, const int* in_sizes, int n_in,
                              void* d_out, int out_size, void* d_ws, size_t ws_size,
                              hipStream_t stream) {
    const float* x  = (const float*)d_in[0];  // [T, H] fp32
    const float* gw = (const float*)d_in[1];  // [I, H] fp32
    const float* uw = (const float*)d_in[2];  // [I, H] fp32
    const float* dw = (const float*)d_in[3];  // [H, I] fp32
    float* out = (float*)d_out;               // [T, H] fp32

    // Workspace (bf16): x_bf [T*H], gw_bf/uw_bf/dw_bf [I*H], hbuf [T*I].
    bf16_t* xb = (bf16_t*)d_ws;
    bf16_t* gb = xb + (size_t)T_DIM * H_DIM;
    bf16_t* ub = gb + (size_t)I_DIM * H_DIM;
    bf16_t* db = ub + (size_t)I_DIM * H_DIM;
    bf16_t* hb = db + (size_t)I_DIM * H_DIM;

    cvt_kernel<<<2048, 256, 0, stream>>>(x, gw, uw, dw, xb, gb, ub, db);
    gateup_kernel<<<dim3(T_DIM / 256, I_DIM / 128), 512, 0, stream>>>(xb, gb, ub, hb);
    down_kernel<<<dim3(T_DIM / 256, H_DIM / 256), 512, 0, stream>>>(hb, db, out);
}